// Round 4
// baseline (597.314 us; speedup 1.0000x reference)
//
#include <hip/hip_runtime.h>

#define NR 8
#define SCAN_BS 256
#define SCAN_E  1024   // elements scanned per block (4 per thread)

// ===========================================================================
// Counting-sort gather path (uses d_ws):
//   ws layout (bytes):
//     cnt     : n_atoms * 4        @ 0
//     offsets : (n_atoms+1) * 4    @ off_offs
//     rank    : n_edges * 4        @ off_rank
//     partial : nb1 * 4            @ off_part
//     inv     : n_edges * 4        @ off_inv
// Contract gathers hs/basis/dn directly per edge via inv (inputs are 76 MB,
// L3-resident) — no materialized per-edge moment records.
// Fallback path (ws too small): round-1 atomic-accumulate version.
// ===========================================================================

__global__ void count_kernel(const int* __restrict__ idx,
                             int* __restrict__ cnt,
                             int* __restrict__ rank, int n_edges) {
    int e = blockIdx.x * blockDim.x + threadIdx.x;
    if (e < n_edges) rank[e] = atomicAdd(&cnt[idx[e]], 1);
}

__global__ void scan1_kernel(const int* __restrict__ cnt,
                             int* __restrict__ scanned,
                             int* __restrict__ partial, int n) {
    __shared__ int sh[SCAN_BS];
    int b = blockIdx.x, t = threadIdx.x;
    int base = b * SCAN_E + t * 4;
    int c0 = (base + 0 < n) ? cnt[base + 0] : 0;
    int c1 = (base + 1 < n) ? cnt[base + 1] : 0;
    int c2 = (base + 2 < n) ? cnt[base + 2] : 0;
    int c3 = (base + 3 < n) ? cnt[base + 3] : 0;
    int s = c0 + c1 + c2 + c3;
    sh[t] = s;
    __syncthreads();
    for (int off = 1; off < SCAN_BS; off <<= 1) {
        int v = (t >= off) ? sh[t - off] : 0;
        __syncthreads();
        sh[t] += v;
        __syncthreads();
    }
    int incl = sh[t];
    int excl = incl - s;
    if (base + 0 < n) scanned[base + 0] = excl;
    if (base + 1 < n) scanned[base + 1] = excl + c0;
    if (base + 2 < n) scanned[base + 2] = excl + c0 + c1;
    if (base + 3 < n) scanned[base + 3] = excl + c0 + c1 + c2;
    if (t == SCAN_BS - 1) partial[b] = incl;
}

__global__ void scan2_kernel(int* __restrict__ partial, int nb) {
    __shared__ int sh[1024];
    int t = threadIdx.x;
    int v = (t < nb) ? partial[t] : 0;
    sh[t] = v;
    __syncthreads();
    for (int off = 1; off < 1024; off <<= 1) {
        int u = (t >= off) ? sh[t - off] : 0;
        __syncthreads();
        sh[t] += u;
        __syncthreads();
    }
    if (t < nb) partial[t] = sh[t] - v;   // exclusive
}

__global__ void scan3_kernel(int* __restrict__ offsets,
                             const int* __restrict__ partial,
                             int n, int total) {
    int i = blockIdx.x * blockDim.x + threadIdx.x;
    if (i < n) offsets[i] += partial[i >> 10];   // SCAN_E == 1024
    if (i == 0) offsets[n] = total;
}

__global__ void inv_kernel(const int* __restrict__ idx,
                           const int* __restrict__ rank,
                           const int* __restrict__ offsets,
                           int* __restrict__ inv, int n_edges) {
    int e = blockIdx.x * blockDim.x + threadIdx.x;
    if (e >= n_edges) return;
    int slot = offsets[idx[e]] + rank[e];
    inv[slot] = e;
}

// One wave per atom: gather this atom's edges straight from the inputs,
// accumulate ZM (lanes 0..7) and FM (lanes 8..31), contract, write outputs.
__global__ void __launch_bounds__(256) contract_gather_kernel(
        const float* __restrict__ dn,
        const float* __restrict__ hs,
        const float* __restrict__ basis,
        const int*   __restrict__ inv,
        const int*   __restrict__ offsets,
        float* __restrict__ out, int n_atoms) {
    int atom = blockIdx.x * 4 + (threadIdx.x >> 6);
    if (atom >= n_atoms) return;
    int lane = threadIdx.x & 63;

    int start = offsets[atom];
    int end   = offsets[atom + 1];

    // lane roles for the accumulator x:
    //   lane 0..7   : ZM[lane]           += hs[e][lane]   * basis[e][lane]
    //   lane 8..31  : FM[s][i] (k=lane-8, s=k/3, i=k%3)
    //                                    += hs[e][s]*basis[e][s]*dn[e][i]
    // per edge, v(lane) holds: hs[0..7] | basis[0..7] | dn[0..2] | 0
    int k   = lane - 8;
    int s_i = k / 3;                 // garbage for lane<8 / lane>=32, unused
    int d_i = k - s_i * 3;
    int p_idx = (lane < 8) ? lane : s_i;       // hs component
    int q_idx = p_idx + 8;                     // basis component
    int m_idx = 16 + d_i;                      // dn component (lanes 8..31)
    if (m_idx < 0)  m_idx = 0;                 // keep shfl index valid
    if (m_idx > 18) m_idx = 18;

    float x = 0.f;
    for (int b = start; b < end; ++b) {
        int e = inv[b];
        const float* src = (lane < 8)  ? (hs    + (size_t)e * 8 + lane)
                         : (lane < 16) ? (basis + (size_t)e * 8 + (lane - 8))
                                       : (dn    + (size_t)e * 3 + (lane - 16));
        float v = (lane < 19) ? *src : 0.f;
        float a  = __shfl(v, p_idx);
        float bb = __shfl(v, q_idx);
        float m  = (lane < 8) ? 1.0f : __shfl(v, m_idx);
        x += a * bb * m;
    }

    int r = lane >> 3;
    int s = lane & 7;

    float zr  = __shfl(x, r);
    float fr0 = __shfl(x, 8 + r * 3 + 0);
    float fr1 = __shfl(x, 8 + r * 3 + 1);
    float fr2 = __shfl(x, 8 + r * 3 + 2);
    float fs0 = __shfl(x, 8 + s * 3 + 0);
    float fs1 = __shfl(x, 8 + s * 3 + 1);
    float fs2 = __shfl(x, 8 + s * 3 + 2);

    float hs1 = fr0 * fs0 + fr1 * fs1 + fr2 * fs2;

    float* zrow = out + (size_t)atom * 72;
    float* prow = out + (size_t)n_atoms * 72 + (size_t)atom * 192;

    if (lane < 8) zrow[lane] = x;       // ZM  (h_s0)
    zrow[8 + lane] = hs1;               // h_s1[r][s]

    prow[lane]       = zr * fs0;        // h_p[i=0][r][s]
    prow[64 + lane]  = zr * fs1;        // h_p[i=1]
    prow[128 + lane] = zr * fs2;        // h_p[i=2]
}

// --------------------- fallback (atomic) kernels ---------------------------

__global__ void zero_acc_kernel(float* __restrict__ out, int n_atoms) {
    int tid = blockIdx.x * blockDim.x + threadIdx.x;
    if (tid >= n_atoms * 8) return;
    int atom = tid >> 3;
    int q    = tid & 7;
    float4 z = make_float4(0.f, 0.f, 0.f, 0.f);
    if (q < 2) {
        reinterpret_cast<float4*>(out + (size_t)atom * 72)[q] = z;
    } else {
        reinterpret_cast<float4*>(out + (size_t)n_atoms * 72 + (size_t)atom * 192)[q - 2] = z;
    }
}

__global__ void scatter_atomic_kernel(const float* __restrict__ dn,
                                      const float* __restrict__ hs,
                                      const float* __restrict__ basis,
                                      const int*   __restrict__ idx,
                                      float* __restrict__ out,
                                      int n_edges, int n_atoms) {
    int e = blockIdx.x * blockDim.x + threadIdx.x;
    if (e >= n_edges) return;

    const float4* hsp = reinterpret_cast<const float4*>(hs + (size_t)e * NR);
    const float4* bp  = reinterpret_cast<const float4*>(basis + (size_t)e * NR);
    float4 h0 = hsp[0], h1 = hsp[1];
    float4 b0 = bp[0],  b1 = bp[1];

    float d0 = dn[(size_t)e * 3 + 0];
    float d1 = dn[(size_t)e * 3 + 1];
    float d2 = dn[(size_t)e * 3 + 2];

    float zm[NR];
    zm[0] = h0.x * b0.x; zm[1] = h0.y * b0.y; zm[2] = h0.z * b0.z; zm[3] = h0.w * b0.w;
    zm[4] = h1.x * b1.x; zm[5] = h1.y * b1.y; zm[6] = h1.z * b1.z; zm[7] = h1.w * b1.w;

    int a = idx[e];
    float* zp = out + (size_t)a * 72;
    float* fp = out + (size_t)n_atoms * 72 + (size_t)a * 192;

#pragma unroll
    for (int r = 0; r < NR; ++r) atomicAdd(zp + r, zm[r]);
#pragma unroll
    for (int r = 0; r < NR; ++r) {
        atomicAdd(fp + r * 3 + 0, zm[r] * d0);
        atomicAdd(fp + r * 3 + 1, zm[r] * d1);
        atomicAdd(fp + r * 3 + 2, zm[r] * d2);
    }
}

__global__ void contract_inplace_kernel(float* __restrict__ out, int n_atoms) {
    int atom = blockIdx.x * 4 + (threadIdx.x >> 6);
    if (atom >= n_atoms) return;
    int lane = threadIdx.x & 63;

    float* zrow = out + (size_t)atom * 72;
    float* prow = out + (size_t)n_atoms * 72 + (size_t)atom * 192;

    float x = 0.f;
    if (lane < 8)       x = zrow[lane];
    else if (lane < 32) x = prow[lane - 8];

    int r = lane >> 3;
    int s = lane & 7;

    float zr  = __shfl(x, r);
    float fr0 = __shfl(x, 8 + r * 3 + 0);
    float fr1 = __shfl(x, 8 + r * 3 + 1);
    float fr2 = __shfl(x, 8 + r * 3 + 2);
    float fs0 = __shfl(x, 8 + s * 3 + 0);
    float fs1 = __shfl(x, 8 + s * 3 + 1);
    float fs2 = __shfl(x, 8 + s * 3 + 2);

    float hs1 = fr0 * fs0 + fr1 * fs1 + fr2 * fs2;

    zrow[8 + lane] = hs1;
    prow[lane]       = zr * fs0;
    prow[64 + lane]  = zr * fs1;
    prow[128 + lane] = zr * fs2;
}

// ---------------------------------------------------------------------------

extern "C" void kernel_launch(void* const* d_in, const int* in_sizes, int n_in,
                              void* d_out, int out_size, void* d_ws, size_t ws_size,
                              hipStream_t stream) {
    const float* dn    = (const float*)d_in[0];
    const float* hs    = (const float*)d_in[1];
    const float* basis = (const float*)d_in[2];
    const int*   idx   = (const int*)d_in[3];
    float* out = (float*)d_out;

    int n_edges = in_sizes[0] / 3;
    int n_atoms = in_sizes[1] / NR;
    int nb1 = (n_atoms + SCAN_E - 1) / SCAN_E;

    size_t off_offs = (size_t)n_atoms * 4;
    size_t off_rank = off_offs + (size_t)(n_atoms + 1) * 4;
    size_t off_part = off_rank + (size_t)n_edges * 4;
    size_t off_inv  = (off_part + (size_t)nb1 * 4 + 255) & ~(size_t)255;
    size_t ws_needed = off_inv + (size_t)n_edges * 4;

    if (ws_size >= ws_needed && nb1 <= 1024) {
        char* ws = (char*)d_ws;
        int* cnt     = (int*)ws;
        int* offsets = (int*)(ws + off_offs);
        int* rank    = (int*)(ws + off_rank);
        int* partial = (int*)(ws + off_part);
        int* inv     = (int*)(ws + off_inv);

        hipMemsetAsync(cnt, 0, (size_t)n_atoms * 4, stream);

        int blk = 256;
        count_kernel<<<(n_edges + blk - 1) / blk, blk, 0, stream>>>(
            idx, cnt, rank, n_edges);

        scan1_kernel<<<nb1, SCAN_BS, 0, stream>>>(cnt, offsets, partial, n_atoms);
        scan2_kernel<<<1, 1024, 0, stream>>>(partial, nb1);
        scan3_kernel<<<(n_atoms + blk - 1) / blk, blk, 0, stream>>>(
            offsets, partial, n_atoms, n_edges);

        inv_kernel<<<(n_edges + blk - 1) / blk, blk, 0, stream>>>(
            idx, rank, offsets, inv, n_edges);

        contract_gather_kernel<<<(n_atoms + 3) / 4, 256, 0, stream>>>(
            dn, hs, basis, inv, offsets, out, n_atoms);
    } else {
        int blk = 256;
        int total = n_atoms * 8;
        zero_acc_kernel<<<(total + blk - 1) / blk, blk, 0, stream>>>(out, n_atoms);
        scatter_atomic_kernel<<<(n_edges + blk - 1) / blk, blk, 0, stream>>>(
            dn, hs, basis, idx, out, n_edges, n_atoms);
        contract_inplace_kernel<<<(n_atoms + 3) / 4, 256, 0, stream>>>(out, n_atoms);
    }
}

// Round 5
// 404.848 us; speedup vs baseline: 1.4754x; 1.4754x over previous
//
#include <hip/hip_runtime.h>

#define NR 8
#define SCAN_BS 256
#define SCAN_E  1024   // elements scanned per block (4 per thread)

// ===========================================================================
// Counting-sort + compact-record path (uses d_ws):
//   record per edge slot = 12 floats (48B, 16B-aligned): zm[8], dn[3], pad
//   ws layout (bytes):
//     cnt     : n_atoms * 4        @ 0
//     offsets : (n_atoms+1) * 4    @ off_offs
//     rank    : n_edges * 4        @ off_rank
//     partial : nb1 * 4            @ off_part
//     ordered : n_edges * 12 * 4   @ off_ord
// Fallback path (ws too small): round-1 atomic-accumulate version.
// ===========================================================================

__global__ void count_kernel(const int* __restrict__ idx,
                             int* __restrict__ cnt,
                             int* __restrict__ rank, int n_edges) {
    int e = blockIdx.x * blockDim.x + threadIdx.x;
    if (e < n_edges) rank[e] = atomicAdd(&cnt[idx[e]], 1);
}

__global__ void scan1_kernel(const int* __restrict__ cnt,
                             int* __restrict__ scanned,
                             int* __restrict__ partial, int n) {
    __shared__ int sh[SCAN_BS];
    int b = blockIdx.x, t = threadIdx.x;
    int base = b * SCAN_E + t * 4;
    int c0 = (base + 0 < n) ? cnt[base + 0] : 0;
    int c1 = (base + 1 < n) ? cnt[base + 1] : 0;
    int c2 = (base + 2 < n) ? cnt[base + 2] : 0;
    int c3 = (base + 3 < n) ? cnt[base + 3] : 0;
    int s = c0 + c1 + c2 + c3;
    sh[t] = s;
    __syncthreads();
    for (int off = 1; off < SCAN_BS; off <<= 1) {
        int v = (t >= off) ? sh[t - off] : 0;
        __syncthreads();
        sh[t] += v;
        __syncthreads();
    }
    int incl = sh[t];
    int excl = incl - s;
    if (base + 0 < n) scanned[base + 0] = excl;
    if (base + 1 < n) scanned[base + 1] = excl + c0;
    if (base + 2 < n) scanned[base + 2] = excl + c0 + c1;
    if (base + 3 < n) scanned[base + 3] = excl + c0 + c1 + c2;
    if (t == SCAN_BS - 1) partial[b] = incl;
}

__global__ void scan2_kernel(int* __restrict__ partial, int nb) {
    __shared__ int sh[1024];
    int t = threadIdx.x;
    int v = (t < nb) ? partial[t] : 0;
    sh[t] = v;
    __syncthreads();
    for (int off = 1; off < 1024; off <<= 1) {
        int u = (t >= off) ? sh[t - off] : 0;
        __syncthreads();
        sh[t] += u;
        __syncthreads();
    }
    if (t < nb) partial[t] = sh[t] - v;   // exclusive
}

__global__ void scan3_kernel(int* __restrict__ offsets,
                             const int* __restrict__ partial,
                             int n, int total) {
    int i = blockIdx.x * blockDim.x + threadIdx.x;
    if (i < n) offsets[i] += partial[i >> 10];   // SCAN_E == 1024
    if (i == 0) offsets[n] = total;
}

__global__ void __launch_bounds__(256) scatter12_kernel(
        const float* __restrict__ dn,
        const float* __restrict__ hs,
        const float* __restrict__ basis,
        const int*   __restrict__ idx,
        const int*   __restrict__ offsets,
        const int*   __restrict__ rank,
        float* __restrict__ ordered,
        int n_edges) {
    int e = blockIdx.x * blockDim.x + threadIdx.x;
    if (e >= n_edges) return;

    const float4* hsp = reinterpret_cast<const float4*>(hs + (size_t)e * NR);
    const float4* bp  = reinterpret_cast<const float4*>(basis + (size_t)e * NR);
    float4 h0 = hsp[0], h1 = hsp[1];
    float4 b0 = bp[0],  b1 = bp[1];

    float d0 = dn[(size_t)e * 3 + 0];
    float d1 = dn[(size_t)e * 3 + 1];
    float d2 = dn[(size_t)e * 3 + 2];

    int slot = offsets[idx[e]] + rank[e];
    float4* dst = reinterpret_cast<float4*>(ordered + (size_t)slot * 12);
    dst[0] = make_float4(h0.x * b0.x, h0.y * b0.y, h0.z * b0.z, h0.w * b0.w);
    dst[1] = make_float4(h1.x * b1.x, h1.y * b1.y, h1.z * b1.z, h1.w * b1.w);
    dst[2] = make_float4(d0, d1, d2, 0.f);
}

// Two atoms per wave (one per 32-lane half). Gather + accumulate with
// half-local shuffles, then two full-wave contraction passes.
__global__ void __launch_bounds__(256) contract12_kernel(
        const float* __restrict__ ordered,
        const int* __restrict__ offsets,
        float* __restrict__ out, int n_atoms) {
    int wid  = blockIdx.x * 4 + (threadIdx.x >> 6);   // wave id
    int lane = threadIdx.x & 63;
    int half = lane >> 5;
    int l    = lane & 31;
    int atom = wid * 2 + half;

    bool valid = atom < n_atoms;
    int start = valid ? offsets[atom]     : 0;
    int end   = valid ? offsets[atom + 1] : 0;

    // accumulator roles within half: l<8 -> ZM[l]; l in [8,32) -> FM[s][i],
    //   k=l-8, s=k/3, i=k%3.  record: v[0..7]=zm, v[8..10]=dn.
    int k   = l - 8;
    int s_i = (k >= 0) ? k / 3 : 0;
    int d_i = (k >= 0) ? k - s_i * 3 : 0;
    int base = half << 5;
    int pa = base + ((l < 8) ? l : s_i);   // zm component source lane
    int pm = base + 8 + d_i;               // dn component source lane

    float x = 0.f;
    for (int b = start; b < end; ++b) {
        float v = (l < 12) ? ordered[(size_t)b * 12 + l] : 0.f;
        float a = __shfl(v, pa);
        float m = (l < 8) ? 1.0f : __shfl(v, pm);
        x += a * m;
    }

    int r = lane >> 3;   // output index rs = lane, r,s in [0,8)
    int s = lane & 7;

#pragma unroll
    for (int h = 0; h < 2; ++h) {
        int a2 = wid * 2 + h;
        if (a2 >= n_atoms) break;
        int B = h << 5;

        float zr  = __shfl(x, B + r);
        float fr0 = __shfl(x, B + 8 + r * 3 + 0);
        float fr1 = __shfl(x, B + 8 + r * 3 + 1);
        float fr2 = __shfl(x, B + 8 + r * 3 + 2);
        float fs0 = __shfl(x, B + 8 + s * 3 + 0);
        float fs1 = __shfl(x, B + 8 + s * 3 + 1);
        float fs2 = __shfl(x, B + 8 + s * 3 + 2);
        float zv  = __shfl(x, B + (lane & 7));

        float hs1 = fr0 * fs0 + fr1 * fs1 + fr2 * fs2;

        float* zrow = out + (size_t)a2 * 72;
        float* prow = out + (size_t)n_atoms * 72 + (size_t)a2 * 192;

        if (lane < 8) zrow[lane] = zv;   // h_s0 = ZM
        zrow[8 + lane] = hs1;            // h_s1[r][s]

        prow[lane]       = zr * fs0;     // h_p[i=0][r][s]
        prow[64 + lane]  = zr * fs1;     // h_p[i=1]
        prow[128 + lane] = zr * fs2;     // h_p[i=2]
    }
}

// --------------------- fallback (atomic) kernels ---------------------------

__global__ void zero_acc_kernel(float* __restrict__ out, int n_atoms) {
    int tid = blockIdx.x * blockDim.x + threadIdx.x;
    if (tid >= n_atoms * 8) return;
    int atom = tid >> 3;
    int q    = tid & 7;
    float4 z = make_float4(0.f, 0.f, 0.f, 0.f);
    if (q < 2) {
        reinterpret_cast<float4*>(out + (size_t)atom * 72)[q] = z;
    } else {
        reinterpret_cast<float4*>(out + (size_t)n_atoms * 72 + (size_t)atom * 192)[q - 2] = z;
    }
}

__global__ void scatter_atomic_kernel(const float* __restrict__ dn,
                                      const float* __restrict__ hs,
                                      const float* __restrict__ basis,
                                      const int*   __restrict__ idx,
                                      float* __restrict__ out,
                                      int n_edges, int n_atoms) {
    int e = blockIdx.x * blockDim.x + threadIdx.x;
    if (e >= n_edges) return;

    const float4* hsp = reinterpret_cast<const float4*>(hs + (size_t)e * NR);
    const float4* bp  = reinterpret_cast<const float4*>(basis + (size_t)e * NR);
    float4 h0 = hsp[0], h1 = hsp[1];
    float4 b0 = bp[0],  b1 = bp[1];

    float d0 = dn[(size_t)e * 3 + 0];
    float d1 = dn[(size_t)e * 3 + 1];
    float d2 = dn[(size_t)e * 3 + 2];

    float zm[NR];
    zm[0] = h0.x * b0.x; zm[1] = h0.y * b0.y; zm[2] = h0.z * b0.z; zm[3] = h0.w * b0.w;
    zm[4] = h1.x * b1.x; zm[5] = h1.y * b1.y; zm[6] = h1.z * b1.z; zm[7] = h1.w * b1.w;

    int a = idx[e];
    float* zp = out + (size_t)a * 72;
    float* fp = out + (size_t)n_atoms * 72 + (size_t)a * 192;

#pragma unroll
    for (int r = 0; r < NR; ++r) atomicAdd(zp + r, zm[r]);
#pragma unroll
    for (int r = 0; r < NR; ++r) {
        atomicAdd(fp + r * 3 + 0, zm[r] * d0);
        atomicAdd(fp + r * 3 + 1, zm[r] * d1);
        atomicAdd(fp + r * 3 + 2, zm[r] * d2);
    }
}

__global__ void contract_inplace_kernel(float* __restrict__ out, int n_atoms) {
    int atom = blockIdx.x * 4 + (threadIdx.x >> 6);
    if (atom >= n_atoms) return;
    int lane = threadIdx.x & 63;

    float* zrow = out + (size_t)atom * 72;
    float* prow = out + (size_t)n_atoms * 72 + (size_t)atom * 192;

    float x = 0.f;
    if (lane < 8)       x = zrow[lane];
    else if (lane < 32) x = prow[lane - 8];

    int r = lane >> 3;
    int s = lane & 7;

    float zr  = __shfl(x, r);
    float fr0 = __shfl(x, 8 + r * 3 + 0);
    float fr1 = __shfl(x, 8 + r * 3 + 1);
    float fr2 = __shfl(x, 8 + r * 3 + 2);
    float fs0 = __shfl(x, 8 + s * 3 + 0);
    float fs1 = __shfl(x, 8 + s * 3 + 1);
    float fs2 = __shfl(x, 8 + s * 3 + 2);

    float hs1 = fr0 * fs0 + fr1 * fs1 + fr2 * fs2;

    zrow[8 + lane] = hs1;
    prow[lane]       = zr * fs0;
    prow[64 + lane]  = zr * fs1;
    prow[128 + lane] = zr * fs2;
}

// ---------------------------------------------------------------------------

extern "C" void kernel_launch(void* const* d_in, const int* in_sizes, int n_in,
                              void* d_out, int out_size, void* d_ws, size_t ws_size,
                              hipStream_t stream) {
    const float* dn    = (const float*)d_in[0];
    const float* hs    = (const float*)d_in[1];
    const float* basis = (const float*)d_in[2];
    const int*   idx   = (const int*)d_in[3];
    float* out = (float*)d_out;

    int n_edges = in_sizes[0] / 3;
    int n_atoms = in_sizes[1] / NR;
    int nb1 = (n_atoms + SCAN_E - 1) / SCAN_E;

    size_t off_offs = (size_t)n_atoms * 4;
    size_t off_rank = off_offs + (size_t)(n_atoms + 1) * 4;
    size_t off_part = off_rank + (size_t)n_edges * 4;
    size_t off_ord  = (off_part + (size_t)nb1 * 4 + 255) & ~(size_t)255;
    size_t ws_needed = off_ord + (size_t)n_edges * 12 * 4;

    if (ws_size >= ws_needed && nb1 <= 1024) {
        char* ws = (char*)d_ws;
        int* cnt     = (int*)ws;
        int* offsets = (int*)(ws + off_offs);
        int* rank    = (int*)(ws + off_rank);
        int* partial = (int*)(ws + off_part);
        float* ordered = (float*)(ws + off_ord);

        hipMemsetAsync(cnt, 0, (size_t)n_atoms * 4, stream);

        int blk = 256;
        count_kernel<<<(n_edges + blk - 1) / blk, blk, 0, stream>>>(
            idx, cnt, rank, n_edges);

        scan1_kernel<<<nb1, SCAN_BS, 0, stream>>>(cnt, offsets, partial, n_atoms);
        scan2_kernel<<<1, 1024, 0, stream>>>(partial, nb1);
        scan3_kernel<<<(n_atoms + blk - 1) / blk, blk, 0, stream>>>(
            offsets, partial, n_atoms, n_edges);

        scatter12_kernel<<<(n_edges + blk - 1) / blk, blk, 0, stream>>>(
            dn, hs, basis, idx, offsets, rank, ordered, n_edges);

        // 2 atoms per wave, 4 waves per block -> 8 atoms per block
        contract12_kernel<<<(n_atoms + 7) / 8, 256, 0, stream>>>(
            ordered, offsets, out, n_atoms);
    } else {
        int blk = 256;
        int total = n_atoms * 8;
        zero_acc_kernel<<<(total + blk - 1) / blk, blk, 0, stream>>>(out, n_atoms);
        scatter_atomic_kernel<<<(n_edges + blk - 1) / blk, blk, 0, stream>>>(
            dn, hs, basis, idx, out, n_edges, n_atoms);
        contract_inplace_kernel<<<(n_atoms + 3) / 4, 256, 0, stream>>>(out, n_atoms);
    }
}

// Round 6
// 377.568 us; speedup vs baseline: 1.5820x; 1.0723x over previous
//
#include <hip/hip_runtime.h>

#define NR 8
#define SCAN_BS 256
#define SCAN_E  1024   // elements scanned per block (4 per thread)

// ===========================================================================
// Counting-sort + compact-record + block-staged contract:
//   record per edge slot = 12 floats (48B): zm[8], dn[3], pad
//   ws layout (bytes):
//     cnt     : n_atoms * 4        @ 0
//     offsets : (n_atoms+1) * 4    @ off_offs
//     rank    : n_edges * 4        @ off_rank
//     partial : nb1 * 4            @ off_part
//     ordered : n_edges * 12 * 4   @ off_ord
// contract_fused: 1 block = 64 atoms; gather records -> LDS acc; then pure
// flat-coalesced float4 streaming of h_s (288B/atom) and h_p (768B/atom).
// Fallback path (ws too small): atomic-accumulate version.
// ===========================================================================

__global__ void count_kernel(const int* __restrict__ idx,
                             int* __restrict__ cnt,
                             int* __restrict__ rank, int n_edges) {
    int e = blockIdx.x * blockDim.x + threadIdx.x;
    if (e < n_edges) rank[e] = atomicAdd(&cnt[idx[e]], 1);
}

__global__ void scan1_kernel(const int* __restrict__ cnt,
                             int* __restrict__ scanned,
                             int* __restrict__ partial, int n) {
    __shared__ int sh[SCAN_BS];
    int b = blockIdx.x, t = threadIdx.x;
    int base = b * SCAN_E + t * 4;
    int c0 = (base + 0 < n) ? cnt[base + 0] : 0;
    int c1 = (base + 1 < n) ? cnt[base + 1] : 0;
    int c2 = (base + 2 < n) ? cnt[base + 2] : 0;
    int c3 = (base + 3 < n) ? cnt[base + 3] : 0;
    int s = c0 + c1 + c2 + c3;
    sh[t] = s;
    __syncthreads();
    for (int off = 1; off < SCAN_BS; off <<= 1) {
        int v = (t >= off) ? sh[t - off] : 0;
        __syncthreads();
        sh[t] += v;
        __syncthreads();
    }
    int incl = sh[t];
    int excl = incl - s;
    if (base + 0 < n) scanned[base + 0] = excl;
    if (base + 1 < n) scanned[base + 1] = excl + c0;
    if (base + 2 < n) scanned[base + 2] = excl + c0 + c1;
    if (base + 3 < n) scanned[base + 3] = excl + c0 + c1 + c2;
    if (t == SCAN_BS - 1) partial[b] = incl;
}

__global__ void scan2_kernel(int* __restrict__ partial, int nb) {
    __shared__ int sh[1024];
    int t = threadIdx.x;
    int v = (t < nb) ? partial[t] : 0;
    sh[t] = v;
    __syncthreads();
    for (int off = 1; off < 1024; off <<= 1) {
        int u = (t >= off) ? sh[t - off] : 0;
        __syncthreads();
        sh[t] += u;
        __syncthreads();
    }
    if (t < nb) partial[t] = sh[t] - v;   // exclusive
}

__global__ void scan3_kernel(int* __restrict__ offsets,
                             const int* __restrict__ partial,
                             int n, int total) {
    int i = blockIdx.x * blockDim.x + threadIdx.x;
    if (i < n) offsets[i] += partial[i >> 10];   // SCAN_E == 1024
    if (i == 0) offsets[n] = total;
}

__global__ void __launch_bounds__(256) scatter12_kernel(
        const float* __restrict__ dn,
        const float* __restrict__ hs,
        const float* __restrict__ basis,
        const int*   __restrict__ idx,
        const int*   __restrict__ offsets,
        const int*   __restrict__ rank,
        float* __restrict__ ordered,
        int n_edges) {
    int e = blockIdx.x * blockDim.x + threadIdx.x;
    if (e >= n_edges) return;

    const float4* hsp = reinterpret_cast<const float4*>(hs + (size_t)e * NR);
    const float4* bp  = reinterpret_cast<const float4*>(basis + (size_t)e * NR);
    float4 h0 = hsp[0], h1 = hsp[1];
    float4 b0 = bp[0],  b1 = bp[1];

    float d0 = dn[(size_t)e * 3 + 0];
    float d1 = dn[(size_t)e * 3 + 1];
    float d2 = dn[(size_t)e * 3 + 2];

    int slot = offsets[idx[e]] + rank[e];
    float4* dst = reinterpret_cast<float4*>(ordered + (size_t)slot * 12);
    dst[0] = make_float4(h0.x * b0.x, h0.y * b0.y, h0.z * b0.z, h0.w * b0.w);
    dst[1] = make_float4(h1.x * b1.x, h1.y * b1.y, h1.z * b1.z, h1.w * b1.w);
    dst[2] = make_float4(d0, d1, d2, 0.f);
}

// Block = 64 atoms. Gather records into LDS acc, then flat-coalesced output.
#define FIN_ATOMS 64
__global__ void __launch_bounds__(256) contract_fused_kernel(
        const float* __restrict__ ordered,
        const int* __restrict__ offsets,
        float* __restrict__ out, int n_atoms) {
    __shared__ float sa[FIN_ATOMS][33];   // [atom][32 comps], pad to kill conflicts
    __shared__ int soff[FIN_ATOMS + 1];

    int a0 = blockIdx.x * FIN_ATOMS;
    int t = threadIdx.x;

    if (t < FIN_ATOMS + 1) {
        int a = a0 + t;
        soff[t] = offsets[(a <= n_atoms) ? a : n_atoms];
    }
    __syncthreads();

    // ---- gather phase: 4 waves x 2 atoms/half x 8 passes = 64 atoms ----
    int wave = t >> 6;
    int lane = t & 63;
    int half = lane >> 5;
    int l    = lane & 31;
    // component map: l<8 -> zm[l]; l>=8 -> fm[s][i], k=l-8, s=k/3, i=k%3
    int k    = l - 8;
    int s_i  = (l >= 8) ? (k / 3) : 0;
    int d_i  = (l >= 8) ? (k - s_i * 3) : 0;
    int src1 = (l < 8) ? l : s_i;
    int src2 = 8 + d_i;
    bool isz = (l < 8);

#pragma unroll
    for (int p = 0; p < 8; ++p) {
        int al = p * 8 + wave * 2 + half;
        int atom = a0 + al;
        if (atom < n_atoms) {
            int start = soff[al];
            int end   = soff[al + 1];
            float x = 0.f;
            for (int b = start; b < end; ++b) {
                const float* rec = ordered + (size_t)b * 12;
                float v1 = rec[src1];
                float v2 = rec[src2];
                x = fmaf(v1, isz ? 1.0f : v2, x);
            }
            sa[al][l] = x;
        }
    }
    __syncthreads();

    // ---- streaming output phase: flat float4 over contiguous block regions ----
    // h_s region: 64 atoms * 18 float4 (row = [zm(8) | hs1(64)])
    {
        float4* hs_base = reinterpret_cast<float4*>(out + (size_t)a0 * 72);
        for (int F = t; F < FIN_ATOMS * 18; F += 256) {
            int al = F / 18;
            int kq = F - al * 18;
            if (a0 + al >= n_atoms) break;
            const float* z = sa[al];
            const float* f = z + 8;
            float4 v;
            if (kq < 2) {
                v = make_float4(z[4*kq+0], z[4*kq+1], z[4*kq+2], z[4*kq+3]);
            } else {
                int m = 4 * (kq - 2);
                int r = m >> 3, s = m & 7;
                float fr0 = f[r*3+0], fr1 = f[r*3+1], fr2 = f[r*3+2];
                v.x = fr0*f[(s+0)*3+0] + fr1*f[(s+0)*3+1] + fr2*f[(s+0)*3+2];
                v.y = fr0*f[(s+1)*3+0] + fr1*f[(s+1)*3+1] + fr2*f[(s+1)*3+2];
                v.z = fr0*f[(s+2)*3+0] + fr1*f[(s+2)*3+1] + fr2*f[(s+2)*3+2];
                v.w = fr0*f[(s+3)*3+0] + fr1*f[(s+3)*3+1] + fr2*f[(s+3)*3+2];
            }
            hs_base[F] = v;
        }
    }
    // h_p region: 64 atoms * 48 float4 (row = [3][8][8] flat i*64+r*8+s)
    {
        float4* hp_base = reinterpret_cast<float4*>(
            out + (size_t)n_atoms * 72 + (size_t)a0 * 192);
        for (int F = t; F < FIN_ATOMS * 48; F += 256) {
            int al = F / 48;
            int kq = F - al * 48;
            if (a0 + al >= n_atoms) break;
            const float* z = sa[al];
            const float* f = z + 8;
            int i = kq >> 4;           // kq/16
            int m = (4 * kq) & 63;
            int r = m >> 3, s = m & 7;
            float zr = z[r];
            float4 v = make_float4(zr * f[(s+0)*3+i], zr * f[(s+1)*3+i],
                                   zr * f[(s+2)*3+i], zr * f[(s+3)*3+i]);
            hp_base[F] = v;
        }
    }
}

// --------------------- fallback (atomic) kernels ---------------------------

__global__ void zero_acc_kernel(float* __restrict__ out, int n_atoms) {
    int tid = blockIdx.x * blockDim.x + threadIdx.x;
    if (tid >= n_atoms * 8) return;
    int atom = tid >> 3;
    int q    = tid & 7;
    float4 z = make_float4(0.f, 0.f, 0.f, 0.f);
    if (q < 2) {
        reinterpret_cast<float4*>(out + (size_t)atom * 72)[q] = z;
    } else {
        reinterpret_cast<float4*>(out + (size_t)n_atoms * 72 + (size_t)atom * 192)[q - 2] = z;
    }
}

__global__ void scatter_atomic_kernel(const float* __restrict__ dn,
                                      const float* __restrict__ hs,
                                      const float* __restrict__ basis,
                                      const int*   __restrict__ idx,
                                      float* __restrict__ out,
                                      int n_edges, int n_atoms) {
    int e = blockIdx.x * blockDim.x + threadIdx.x;
    if (e >= n_edges) return;

    const float4* hsp = reinterpret_cast<const float4*>(hs + (size_t)e * NR);
    const float4* bp  = reinterpret_cast<const float4*>(basis + (size_t)e * NR);
    float4 h0 = hsp[0], h1 = hsp[1];
    float4 b0 = bp[0],  b1 = bp[1];

    float d0 = dn[(size_t)e * 3 + 0];
    float d1 = dn[(size_t)e * 3 + 1];
    float d2 = dn[(size_t)e * 3 + 2];

    float zm[NR];
    zm[0] = h0.x * b0.x; zm[1] = h0.y * b0.y; zm[2] = h0.z * b0.z; zm[3] = h0.w * b0.w;
    zm[4] = h1.x * b1.x; zm[5] = h1.y * b1.y; zm[6] = h1.z * b1.z; zm[7] = h1.w * b1.w;

    int a = idx[e];
    float* zp = out + (size_t)a * 72;
    float* fp = out + (size_t)n_atoms * 72 + (size_t)a * 192;

#pragma unroll
    for (int r = 0; r < NR; ++r) atomicAdd(zp + r, zm[r]);
#pragma unroll
    for (int r = 0; r < NR; ++r) {
        atomicAdd(fp + r * 3 + 0, zm[r] * d0);
        atomicAdd(fp + r * 3 + 1, zm[r] * d1);
        atomicAdd(fp + r * 3 + 2, zm[r] * d2);
    }
}

__global__ void contract_inplace_kernel(float* __restrict__ out, int n_atoms) {
    int atom = blockIdx.x * 4 + (threadIdx.x >> 6);
    if (atom >= n_atoms) return;
    int lane = threadIdx.x & 63;

    float* zrow = out + (size_t)atom * 72;
    float* prow = out + (size_t)n_atoms * 72 + (size_t)atom * 192;

    float x = 0.f;
    if (lane < 8)       x = zrow[lane];
    else if (lane < 32) x = prow[lane - 8];

    int r = lane >> 3;
    int s = lane & 7;

    float zr  = __shfl(x, r);
    float fr0 = __shfl(x, 8 + r * 3 + 0);
    float fr1 = __shfl(x, 8 + r * 3 + 1);
    float fr2 = __shfl(x, 8 + r * 3 + 2);
    float fs0 = __shfl(x, 8 + s * 3 + 0);
    float fs1 = __shfl(x, 8 + s * 3 + 1);
    float fs2 = __shfl(x, 8 + s * 3 + 2);

    float hs1 = fr0 * fs0 + fr1 * fs1 + fr2 * fs2;

    zrow[8 + lane] = hs1;
    prow[lane]       = zr * fs0;
    prow[64 + lane]  = zr * fs1;
    prow[128 + lane] = zr * fs2;
}

// ---------------------------------------------------------------------------

extern "C" void kernel_launch(void* const* d_in, const int* in_sizes, int n_in,
                              void* d_out, int out_size, void* d_ws, size_t ws_size,
                              hipStream_t stream) {
    const float* dn    = (const float*)d_in[0];
    const float* hs    = (const float*)d_in[1];
    const float* basis = (const float*)d_in[2];
    const int*   idx   = (const int*)d_in[3];
    float* out = (float*)d_out;

    int n_edges = in_sizes[0] / 3;
    int n_atoms = in_sizes[1] / NR;
    int nb1 = (n_atoms + SCAN_E - 1) / SCAN_E;

    size_t off_offs = (size_t)n_atoms * 4;
    size_t off_rank = off_offs + (size_t)(n_atoms + 1) * 4;
    size_t off_part = off_rank + (size_t)n_edges * 4;
    size_t off_ord  = (off_part + (size_t)nb1 * 4 + 255) & ~(size_t)255;
    size_t ws_needed = off_ord + (size_t)n_edges * 12 * 4;

    if (ws_size >= ws_needed && nb1 <= 1024) {
        char* ws = (char*)d_ws;
        int* cnt     = (int*)ws;
        int* offsets = (int*)(ws + off_offs);
        int* rank    = (int*)(ws + off_rank);
        int* partial = (int*)(ws + off_part);
        float* ordered = (float*)(ws + off_ord);

        hipMemsetAsync(cnt, 0, (size_t)n_atoms * 4, stream);

        int blk = 256;
        count_kernel<<<(n_edges + blk - 1) / blk, blk, 0, stream>>>(
            idx, cnt, rank, n_edges);

        scan1_kernel<<<nb1, SCAN_BS, 0, stream>>>(cnt, offsets, partial, n_atoms);
        scan2_kernel<<<1, 1024, 0, stream>>>(partial, nb1);
        scan3_kernel<<<(n_atoms + blk - 1) / blk, blk, 0, stream>>>(
            offsets, partial, n_atoms, n_edges);

        scatter12_kernel<<<(n_edges + blk - 1) / blk, blk, 0, stream>>>(
            dn, hs, basis, idx, offsets, rank, ordered, n_edges);

        contract_fused_kernel<<<(n_atoms + FIN_ATOMS - 1) / FIN_ATOMS, 256, 0, stream>>>(
            ordered, offsets, out, n_atoms);
    } else {
        int blk = 256;
        int total = n_atoms * 8;
        zero_acc_kernel<<<(total + blk - 1) / blk, blk, 0, stream>>>(out, n_atoms);
        scatter_atomic_kernel<<<(n_edges + blk - 1) / blk, blk, 0, stream>>>(
            dn, hs, basis, idx, out, n_edges, n_atoms);
        contract_inplace_kernel<<<(n_atoms + 3) / 4, 256, 0, stream>>>(out, n_atoms);
    }
}

// Round 7
// 346.797 us; speedup vs baseline: 1.7224x; 1.0887x over previous
//
#include <hip/hip_runtime.h>

#define NR 8
#define SCAN_BS 256
#define SCAN_E  1024   // elements scanned per block (4 per thread)
#define FIN_ATOMS 128

// ===========================================================================
// Counting-sort + bf16 compact-record + block-staged contract:
//   record per edge slot = 12 bf16 (24B): zm[8], dn[3], pad
//   ws layout (bytes):
//     cnt     : n_atoms * 4        @ 0
//     offsets : (n_atoms+1) * 4    @ off_offs
//     rank    : n_edges * 4        @ off_rank
//     partial : nb1 * 4            @ off_part
//     ordered : n_edges * 24      @ off_ord
// contract_fused: 1 block = 128 atoms; gather records -> LDS acc (FM stored
// [i][s] so output phase uses ds_read_b128); then flat-coalesced float4
// streaming of h_s (288B/atom) and h_p (768B/atom).
// Fallback path (ws too small): atomic-accumulate version.
// ===========================================================================

__device__ __forceinline__ unsigned short f2b(float f) {
    unsigned int u = __float_as_uint(f);
    unsigned int r = (u + 0x7FFFu + ((u >> 16) & 1u)) >> 16;   // RNE
    return (unsigned short)r;
}
__device__ __forceinline__ float b2f(unsigned short h) {
    return __uint_as_float(((unsigned int)h) << 16);
}

__global__ void count_kernel(const int* __restrict__ idx,
                             int* __restrict__ cnt,
                             int* __restrict__ rank, int n_edges) {
    int e = blockIdx.x * blockDim.x + threadIdx.x;
    if (e < n_edges) rank[e] = atomicAdd(&cnt[idx[e]], 1);
}

__global__ void scan1_kernel(const int* __restrict__ cnt,
                             int* __restrict__ scanned,
                             int* __restrict__ partial, int n) {
    __shared__ int sh[SCAN_BS];
    int b = blockIdx.x, t = threadIdx.x;
    int base = b * SCAN_E + t * 4;
    int c0 = (base + 0 < n) ? cnt[base + 0] : 0;
    int c1 = (base + 1 < n) ? cnt[base + 1] : 0;
    int c2 = (base + 2 < n) ? cnt[base + 2] : 0;
    int c3 = (base + 3 < n) ? cnt[base + 3] : 0;
    int s = c0 + c1 + c2 + c3;
    sh[t] = s;
    __syncthreads();
    for (int off = 1; off < SCAN_BS; off <<= 1) {
        int v = (t >= off) ? sh[t - off] : 0;
        __syncthreads();
        sh[t] += v;
        __syncthreads();
    }
    int incl = sh[t];
    int excl = incl - s;
    if (base + 0 < n) scanned[base + 0] = excl;
    if (base + 1 < n) scanned[base + 1] = excl + c0;
    if (base + 2 < n) scanned[base + 2] = excl + c0 + c1;
    if (base + 3 < n) scanned[base + 3] = excl + c0 + c1 + c2;
    if (t == SCAN_BS - 1) partial[b] = incl;
}

__global__ void scan2_kernel(int* __restrict__ partial, int nb) {
    __shared__ int sh[1024];
    int t = threadIdx.x;
    int v = (t < nb) ? partial[t] : 0;
    sh[t] = v;
    __syncthreads();
    for (int off = 1; off < 1024; off <<= 1) {
        int u = (t >= off) ? sh[t - off] : 0;
        __syncthreads();
        sh[t] += u;
        __syncthreads();
    }
    if (t < nb) partial[t] = sh[t] - v;   // exclusive
}

__global__ void scan3_kernel(int* __restrict__ offsets,
                             const int* __restrict__ partial,
                             int n, int total) {
    int i = blockIdx.x * blockDim.x + threadIdx.x;
    if (i < n) offsets[i] += partial[i >> 10];   // SCAN_E == 1024
    if (i == 0) offsets[n] = total;
}

__global__ void __launch_bounds__(256) scatter24_kernel(
        const float* __restrict__ dn,
        const float* __restrict__ hs,
        const float* __restrict__ basis,
        const int*   __restrict__ idx,
        const int*   __restrict__ offsets,
        const int*   __restrict__ rank,
        unsigned short* __restrict__ ordered,
        int n_edges) {
    int e = blockIdx.x * blockDim.x + threadIdx.x;
    if (e >= n_edges) return;

    const float4* hsp = reinterpret_cast<const float4*>(hs + (size_t)e * NR);
    const float4* bp  = reinterpret_cast<const float4*>(basis + (size_t)e * NR);
    float4 h0 = hsp[0], h1 = hsp[1];
    float4 b0 = bp[0],  b1 = bp[1];

    float d0 = dn[(size_t)e * 3 + 0];
    float d1 = dn[(size_t)e * 3 + 1];
    float d2 = dn[(size_t)e * 3 + 2];

    unsigned int w0 = (unsigned int)f2b(h0.x * b0.x) | ((unsigned int)f2b(h0.y * b0.y) << 16);
    unsigned int w1 = (unsigned int)f2b(h0.z * b0.z) | ((unsigned int)f2b(h0.w * b0.w) << 16);
    unsigned int w2 = (unsigned int)f2b(h1.x * b1.x) | ((unsigned int)f2b(h1.y * b1.y) << 16);
    unsigned int w3 = (unsigned int)f2b(h1.z * b1.z) | ((unsigned int)f2b(h1.w * b1.w) << 16);
    unsigned int w4 = (unsigned int)f2b(d0) | ((unsigned int)f2b(d1) << 16);
    unsigned int w5 = (unsigned int)f2b(d2);

    int slot = offsets[idx[e]] + rank[e];
    uint2* dst = reinterpret_cast<uint2*>(ordered + (size_t)slot * 12);   // 24B, 8B-aligned
    dst[0] = make_uint2(w0, w1);
    dst[1] = make_uint2(w2, w3);
    dst[2] = make_uint2(w4, w5);
}

// Block = 128 atoms. Gather bf16 records into LDS acc (FM as [i][s]), then
// flat-coalesced float4 streaming of both output regions.
__global__ void __launch_bounds__(256) contract_fused_kernel(
        const unsigned short* __restrict__ ordered,
        const int* __restrict__ offsets,
        float* __restrict__ out, int n_atoms) {
    __shared__ float sa[FIN_ATOMS][36];   // [atom][comp]; stride 36 => 16B-aligned rows
    __shared__ int soff[FIN_ATOMS + 1];

    int a0 = blockIdx.x * FIN_ATOMS;
    int t = threadIdx.x;

    if (t < FIN_ATOMS + 1) {
        int a = a0 + t;
        soff[t] = offsets[(a <= n_atoms) ? a : n_atoms];
    }
    __syncthreads();

    // ---- gather: wave w owns atoms [w*32, w*32+32); 2 atoms per pass ----
    int wave = t >> 6;
    int lane = t & 63;
    int half = lane >> 5;
    int l    = lane & 31;
    // comp map: l<8 -> ZM[l]; l>=8 -> FM[i][s], k=l-8, i=k>>3, s=k&7
    int k    = l - 8;
    int s_i  = k & 7;
    int i_i  = k >> 3;
    int src1 = (l < 8) ? l : s_i;      // zm component in record
    int src2 = 8 + ((l < 8) ? 0 : i_i); // dn component in record
    bool isz = (l < 8);

#pragma unroll 4
    for (int p = 0; p < FIN_ATOMS / 8; ++p) {
        int al = wave * (FIN_ATOMS / 4) + p * 2 + half;
        int atom = a0 + al;
        if (atom < n_atoms) {
            int start = soff[al];
            int end   = soff[al + 1];
            float x = 0.f;
            for (int b = start; b < end; ++b) {
                const unsigned short* rec = ordered + (size_t)b * 12;
                float v1 = b2f(rec[src1]);
                float v2 = isz ? 1.0f : b2f(rec[src2]);
                x = fmaf(v1, v2, x);
            }
            sa[al][l] = x;
        }
    }
    __syncthreads();

    // ---- streaming output ----
    // h_s region: FIN atoms * 18 float4; row = [zm(8) | hs1(64)]
    {
        float4* hs_base = reinterpret_cast<float4*>(out + (size_t)a0 * 72);
        for (int F = t; F < FIN_ATOMS * 18; F += 256) {
            int al = F / 18;
            int kq = F - al * 18;
            if (a0 + al >= n_atoms) break;
            const float* z = sa[al];
            float4 v;
            if (kq < 2) {
                v = reinterpret_cast<const float4*>(z)[kq];
            } else {
                int m = 4 * (kq - 2);
                int r = m >> 3, s = m & 7;            // s in {0,4}
                float  fr0 = z[8 + 0 * 8 + r];
                float  fr1 = z[8 + 1 * 8 + r];
                float  fr2 = z[8 + 2 * 8 + r];
                float4 fs0 = *reinterpret_cast<const float4*>(z + 8 + 0 * 8 + s);
                float4 fs1 = *reinterpret_cast<const float4*>(z + 8 + 1 * 8 + s);
                float4 fs2 = *reinterpret_cast<const float4*>(z + 8 + 2 * 8 + s);
                v.x = fr0 * fs0.x + fr1 * fs1.x + fr2 * fs2.x;
                v.y = fr0 * fs0.y + fr1 * fs1.y + fr2 * fs2.y;
                v.z = fr0 * fs0.z + fr1 * fs1.z + fr2 * fs2.z;
                v.w = fr0 * fs0.w + fr1 * fs1.w + fr2 * fs2.w;
            }
            hs_base[F] = v;
        }
    }
    // h_p region: FIN atoms * 48 float4; row flat = i*64 + r*8 + s
    {
        float4* hp_base = reinterpret_cast<float4*>(
            out + (size_t)n_atoms * 72 + (size_t)a0 * 192);
        for (int F = t; F < FIN_ATOMS * 48; F += 256) {
            int al = F / 48;
            int kq = F - al * 48;
            if (a0 + al >= n_atoms) break;
            const float* z = sa[al];
            int i = kq >> 4;
            int m = (4 * kq) & 63;
            int r = m >> 3, s = m & 7;                // s in {0,4}
            float  zr = z[r];
            float4 fv = *reinterpret_cast<const float4*>(z + 8 + i * 8 + s);
            hp_base[F] = make_float4(zr * fv.x, zr * fv.y, zr * fv.z, zr * fv.w);
        }
    }
}

// --------------------- fallback (atomic) kernels ---------------------------

__global__ void zero_acc_kernel(float* __restrict__ out, int n_atoms) {
    int tid = blockIdx.x * blockDim.x + threadIdx.x;
    if (tid >= n_atoms * 8) return;
    int atom = tid >> 3;
    int q    = tid & 7;
    float4 z = make_float4(0.f, 0.f, 0.f, 0.f);
    if (q < 2) {
        reinterpret_cast<float4*>(out + (size_t)atom * 72)[q] = z;
    } else {
        reinterpret_cast<float4*>(out + (size_t)n_atoms * 72 + (size_t)atom * 192)[q - 2] = z;
    }
}

__global__ void scatter_atomic_kernel(const float* __restrict__ dn,
                                      const float* __restrict__ hs,
                                      const float* __restrict__ basis,
                                      const int*   __restrict__ idx,
                                      float* __restrict__ out,
                                      int n_edges, int n_atoms) {
    int e = blockIdx.x * blockDim.x + threadIdx.x;
    if (e >= n_edges) return;

    const float4* hsp = reinterpret_cast<const float4*>(hs + (size_t)e * NR);
    const float4* bp  = reinterpret_cast<const float4*>(basis + (size_t)e * NR);
    float4 h0 = hsp[0], h1 = hsp[1];
    float4 b0 = bp[0],  b1 = bp[1];

    float d0 = dn[(size_t)e * 3 + 0];
    float d1 = dn[(size_t)e * 3 + 1];
    float d2 = dn[(size_t)e * 3 + 2];

    float zm[NR];
    zm[0] = h0.x * b0.x; zm[1] = h0.y * b0.y; zm[2] = h0.z * b0.z; zm[3] = h0.w * b0.w;
    zm[4] = h1.x * b1.x; zm[5] = h1.y * b1.y; zm[6] = h1.z * b1.z; zm[7] = h1.w * b1.w;

    int a = idx[e];
    float* zp = out + (size_t)a * 72;
    float* fp = out + (size_t)n_atoms * 72 + (size_t)a * 192;

#pragma unroll
    for (int r = 0; r < NR; ++r) atomicAdd(zp + r, zm[r]);
#pragma unroll
    for (int r = 0; r < NR; ++r) {
        atomicAdd(fp + r * 3 + 0, zm[r] * d0);
        atomicAdd(fp + r * 3 + 1, zm[r] * d1);
        atomicAdd(fp + r * 3 + 2, zm[r] * d2);
    }
}

__global__ void contract_inplace_kernel(float* __restrict__ out, int n_atoms) {
    int atom = blockIdx.x * 4 + (threadIdx.x >> 6);
    if (atom >= n_atoms) return;
    int lane = threadIdx.x & 63;

    float* zrow = out + (size_t)atom * 72;
    float* prow = out + (size_t)n_atoms * 72 + (size_t)atom * 192;

    float x = 0.f;
    if (lane < 8)       x = zrow[lane];
    else if (lane < 32) x = prow[lane - 8];

    int r = lane >> 3;
    int s = lane & 7;

    float zr  = __shfl(x, r);
    float fr0 = __shfl(x, 8 + r * 3 + 0);
    float fr1 = __shfl(x, 8 + r * 3 + 1);
    float fr2 = __shfl(x, 8 + r * 3 + 2);
    float fs0 = __shfl(x, 8 + s * 3 + 0);
    float fs1 = __shfl(x, 8 + s * 3 + 1);
    float fs2 = __shfl(x, 8 + s * 3 + 2);

    float hs1 = fr0 * fs0 + fr1 * fs1 + fr2 * fs2;

    zrow[8 + lane] = hs1;
    prow[lane]       = zr * fs0;
    prow[64 + lane]  = zr * fs1;
    prow[128 + lane] = zr * fs2;
}

// ---------------------------------------------------------------------------

extern "C" void kernel_launch(void* const* d_in, const int* in_sizes, int n_in,
                              void* d_out, int out_size, void* d_ws, size_t ws_size,
                              hipStream_t stream) {
    const float* dn    = (const float*)d_in[0];
    const float* hs    = (const float*)d_in[1];
    const float* basis = (const float*)d_in[2];
    const int*   idx   = (const int*)d_in[3];
    float* out = (float*)d_out;

    int n_edges = in_sizes[0] / 3;
    int n_atoms = in_sizes[1] / NR;
    int nb1 = (n_atoms + SCAN_E - 1) / SCAN_E;

    size_t off_offs = (size_t)n_atoms * 4;
    size_t off_rank = off_offs + (size_t)(n_atoms + 1) * 4;
    size_t off_part = off_rank + (size_t)n_edges * 4;
    size_t off_ord  = (off_part + (size_t)nb1 * 4 + 255) & ~(size_t)255;
    size_t ws_needed = off_ord + (size_t)n_edges * 24;

    if (ws_size >= ws_needed && nb1 <= 1024) {
        char* ws = (char*)d_ws;
        int* cnt     = (int*)ws;
        int* offsets = (int*)(ws + off_offs);
        int* rank    = (int*)(ws + off_rank);
        int* partial = (int*)(ws + off_part);
        unsigned short* ordered = (unsigned short*)(ws + off_ord);

        hipMemsetAsync(cnt, 0, (size_t)n_atoms * 4, stream);

        int blk = 256;
        count_kernel<<<(n_edges + blk - 1) / blk, blk, 0, stream>>>(
            idx, cnt, rank, n_edges);

        scan1_kernel<<<nb1, SCAN_BS, 0, stream>>>(cnt, offsets, partial, n_atoms);
        scan2_kernel<<<1, 1024, 0, stream>>>(partial, nb1);
        scan3_kernel<<<(n_atoms + blk - 1) / blk, blk, 0, stream>>>(
            offsets, partial, n_atoms, n_edges);

        scatter24_kernel<<<(n_edges + blk - 1) / blk, blk, 0, stream>>>(
            dn, hs, basis, idx, offsets, rank, ordered, n_edges);

        contract_fused_kernel<<<(n_atoms + FIN_ATOMS - 1) / FIN_ATOMS, 256, 0, stream>>>(
            ordered, offsets, out, n_atoms);
    } else {
        int blk = 256;
        int total = n_atoms * 8;
        zero_acc_kernel<<<(total + blk - 1) / blk, blk, 0, stream>>>(out, n_atoms);
        scatter_atomic_kernel<<<(n_edges + blk - 1) / blk, blk, 0, stream>>>(
            dn, hs, basis, idx, out, n_edges, n_atoms);
        contract_inplace_kernel<<<(n_atoms + 3) / 4, 256, 0, stream>>>(out, n_atoms);
    }
}